// Round 6
// baseline (206.197 us; speedup 1.0000x reference)
//
#include <hip/hip_runtime.h>

typedef __bf16 bf16x8 __attribute__((ext_vector_type(8)));
typedef float  f32x4  __attribute__((ext_vector_type(4)));
typedef unsigned short ushortx8 __attribute__((ext_vector_type(8)));
typedef unsigned short ushortx4 __attribute__((ext_vector_type(4)));

static __device__ __forceinline__ unsigned short f2bf(float f) {
  unsigned int u = __builtin_bit_cast(unsigned int, f);
  u += 0x7FFFu + ((u >> 16) & 1u);
  return (unsigned short)(u >> 16);
}
static __device__ __forceinline__ unsigned short f2bf_fast(float f) {  // round-half-up
  unsigned int u = __builtin_bit_cast(unsigned int, f);
  return (unsigned short)((u + 0x8000u) >> 16);
}

#define GLL16(gp, lp) __builtin_amdgcn_global_load_lds(                       \
    (const __attribute__((address_space(1))) void*)(gp),                      \
    (__attribute__((address_space(3))) void*)(lp), 16, 0, 0)

// ---------------- prep: z<4 -> transpose+cast W; z>=4 -> cast X fp32->bf16 ----------------
__global__ __launch_bounds__(256) void prep_kernel(const float* __restrict__ X,
                                                   const float* __restrict__ W0,
                                                   const float* __restrict__ W1,
                                                   const float* __restrict__ W2,
                                                   const float* __restrict__ W3,
                                                   unsigned short* __restrict__ Xbf,
                                                   unsigned short* __restrict__ D0,
                                                   unsigned short* __restrict__ D1,
                                                   unsigned short* __restrict__ D2,
                                                   unsigned short* __restrict__ D3) {
  int z = blockIdx.z;
  if (z >= 4) {  // cast 4096x1024 fp32 -> bf16; z in {4,5}
    long bid = (long)(z - 4) * 1024 + blockIdx.y * 32 + blockIdx.x;
    int tl = threadIdx.y * 32 + threadIdx.x;
    long i = bid * 2048 + (long)tl * 8;
    float4 f0 = *(const float4*)(X + i);
    float4 f1 = *(const float4*)(X + i + 4);
    ushortx8 u;
    u[0] = f2bf(f0.x); u[1] = f2bf(f0.y); u[2] = f2bf(f0.z); u[3] = f2bf(f0.w);
    u[4] = f2bf(f1.x); u[5] = f2bf(f1.y); u[6] = f2bf(f1.z); u[7] = f2bf(f1.w);
    *(ushortx8*)(Xbf + i) = u;
    return;
  }
  const float* src = (z == 0) ? W0 : (z == 1) ? W1 : (z == 2) ? W2 : W3;
  unsigned short* dst = (z == 0) ? D0 : (z == 1) ? D1 : (z == 2) ? D2 : D3;
  const int R = 1024, C = 1024;
  __shared__ unsigned short t[32][33];
  int c = blockIdx.x * 32 + threadIdx.x;
#pragma unroll
  for (int i = 0; i < 4; ++i) {
    int r = blockIdx.y * 32 + threadIdx.y + i * 8;
    t[threadIdx.y + i * 8][threadIdx.x] = f2bf(src[(size_t)r * C + c]);
  }
  __syncthreads();
  int rr = blockIdx.y * 32 + threadIdx.x;
#pragma unroll
  for (int i = 0; i < 4; ++i) {
    int cc = blockIdx.x * 32 + threadIdx.y + i * 8;
    dst[(size_t)cc * R + rr] = t[threadIdx.x][threadIdx.y + i * 8];
  }
}

// ---------------- QKV GEMM: 256x256 tile, BK=32 K-tiles, 4-deep LDS ring, counted vmcnt ----
// One fused GEMM over M=4096, N=3072 (z = 0:Q RoPE+prescale, 1:K RoPE, 2:V^T).
// Tile t lives in buf[t&3]; during tile t's 2 phases we stage tile t+3 into buf[(t+3)&3]
// (= buf[(t-1)&3], dead since tile t-1's trailing barrier -> no WAR race).
// Single counted wait per tile: vmcnt(8) before Ph1's trailing barrier leaves exactly
// t+2 (4 loads) + t+3 (4 loads) in flight and secures t+1 at a 4-phase issue distance.
// Tail tiles stage into a dummy LDS region to keep the vmcnt arithmetic uniform.
__global__ __launch_bounds__(512, 2) void gemm256_kernel(
    const unsigned short* __restrict__ A,
    const unsigned short* __restrict__ BT0,
    const unsigned short* __restrict__ BT1,
    const unsigned short* __restrict__ BT2,
    unsigned short* __restrict__ outQ,
    unsigned short* __restrict__ outK,
    unsigned short* __restrict__ outVT,
    const int* __restrict__ pos_ids,
    const float* __restrict__ cosb,
    const float* __restrict__ sinb) {
  const int K = 1024;
  // chunked XCD swizzle: xcd = blockIdx.x (grid 8x24), 24 consecutive ids per XCD
  int id = blockIdx.x * 24 + blockIdx.y;
  int z = id >> 6;            // 64 blocks per z
  int r_ = id & 63;
  int n_idx = r_ & 3, m_idx = r_ >> 2;
  const unsigned short* BT = (z == 0) ? BT0 : (z == 1 ? BT1 : BT2);
  int m0 = m_idx * 256, n0 = n_idx * 256;
  int t = threadIdx.x, lane = t & 63, w = t >> 6;
  int wy = w >> 2, wx = w & 3;          // 2M x 4N waves
  int n16 = lane & 15, quad = lane >> 4;

  // 4-buffer ring: [buf][row 0..255][32 elems] per matrix; 64 KiB each matrix
  __shared__ __align__(16) unsigned short sA[4][256][32];
  __shared__ __align__(16) unsigned short sB[4][256][32];
  __shared__ __align__(16) unsigned short sDummy[512];  // tail-staging sink (never read)

  // staging: wave w covers rows w*16+[0,16) (+128 for second GLL); lane: row += lane>>2,
  // LDS chunk = lane&3. Global source chunk pre-swizzled so LDS-linear dest + swizzled
  // ds_read retrieve global chunk quad: sw(row) = (row&3) ^ ((row>>2)&3).
  int schunk = (lane & 3) ^ ((lane >> 2) & 3) ^ ((lane >> 4) & 3);
  const unsigned short* gA0 = A + (size_t)(m0 + w * 16 + (lane >> 2)) * K + schunk * 8;
  const unsigned short* gB0 = BT + (size_t)(n0 + w * 16 + (lane >> 2)) * K + schunk * 8;
  const size_t rstep = (size_t)128 * K;  // +128 rows (elements)
  unsigned short* stA = &sA[0][w * 16][0];
  unsigned short* stB = &sB[0][w * 16][0];

  // ds_read: chunk = quad ^ sw(row); row = 16*m + n16 -> sw = (n16&3) ^ (n16>>2)
  int cs = (quad ^ (n16 & 3) ^ (n16 >> 2)) * 8;
  const unsigned short* rdA = &sA[0][wy * 128 + n16][0] + cs;
  const unsigned short* rdB = &sB[0][wx * 64 + n16][0] + cs;

  f32x4 acc[8][4];
#pragma unroll
  for (int i = 0; i < 8; ++i)
#pragma unroll
    for (int j = 0; j < 4; ++j) acc[i][j] = f32x4{0.f, 0.f, 0.f, 0.f};

  bf16x8 a[4], b[4];

#define STG_A(tt, d0, d1)                                                             \
  do {                                                                                \
    GLL16(gA0 + (size_t)(tt) * 32, (d0));                                             \
    GLL16(gA0 + (size_t)(tt) * 32 + rstep, (d1));                                     \
  } while (0)
#define STG_B(tt, d0, d1)                                                             \
  do {                                                                                \
    GLL16(gB0 + (size_t)(tt) * 32, (d0));                                             \
    GLL16(gB0 + (size_t)(tt) * 32 + rstep, (d1));                                     \
  } while (0)

#define RD_A4(bufi, mh)                                                               \
  do {                                                                                \
    _Pragma("unroll") for (int i = 0; i < 4; ++i)                                     \
      a[i] = *(const bf16x8*)(rdA + (bufi) * 8192 + ((mh) * 64 + i * 16) * 32);       \
  } while (0)
#define RD_B4(bufi)                                                                   \
  do {                                                                                \
    _Pragma("unroll") for (int jb = 0; jb < 4; ++jb)                                  \
      b[jb] = *(const bf16x8*)(rdB + (bufi) * 8192 + (jb) * 16 * 32);                 \
  } while (0)

#define MMQ(mh, nh)                                                                   \
  do {                                                                                \
    _Pragma("unroll") for (int i = 0; i < 4; ++i)                                     \
      _Pragma("unroll") for (int jj = 0; jj < 2; ++jj)                                \
        acc[(mh) * 4 + i][(nh) * 2 + jj] = __builtin_amdgcn_mfma_f32_16x16x32_bf16(   \
            a[i], b[(nh) * 2 + jj], acc[(mh) * 4 + i][(nh) * 2 + jj], 0, 0, 0);       \
  } while (0)

  // prologue: stage tiles 0,1,2 (12 loads); vmcnt(8) -> tile0 landed, t1/t2 in flight
  STG_A(0, stA, stA + 4096);               STG_B(0, stB, stB + 4096);
  STG_A(1, stA + 8192, stA + 12288);       STG_B(1, stB + 8192, stB + 12288);
  STG_A(2, stA + 16384, stA + 20480);      STG_B(2, stB + 16384, stB + 20480);
  asm volatile("s_waitcnt vmcnt(8)" ::: "memory");
  __builtin_amdgcn_s_barrier();

#pragma unroll 4
  for (int kt = 0; kt < 32; ++kt) {
    int buf = kt & 3;
    int pf = kt + 3;
    bool ok = pf < 32;
    int pfc = ok ? pf : 31;
    unsigned short* dA0 = ok ? (stA + (pf & 3) * 8192) : sDummy;
    unsigned short* dA1 = ok ? (dA0 + 4096) : sDummy;
    unsigned short* dB0 = ok ? (stB + (pf & 3) * 8192) : sDummy;
    unsigned short* dB1 = ok ? (dB0 + 4096) : sDummy;
    // ---- Ph0: quadrants (0,0),(0,1); stage A of tile kt+3
    RD_A4(buf, 0);
    RD_B4(buf);
    STG_A(pfc, dA0, dA1);
    __builtin_amdgcn_s_barrier();
    __builtin_amdgcn_s_setprio(1);
    MMQ(0, 0); MMQ(0, 1);
    __builtin_amdgcn_s_setprio(0);
    __builtin_amdgcn_sched_barrier(0);
    __builtin_amdgcn_s_barrier();
    // ---- Ph1: quadrants (1,0),(1,1); stage B of tile kt+3; counted wait
    RD_A4(buf, 1);
    STG_B(pfc, dB0, dB1);
    __builtin_amdgcn_s_barrier();
    __builtin_amdgcn_s_setprio(1);
    MMQ(1, 0); MMQ(1, 1);
    __builtin_amdgcn_s_setprio(0);
    __builtin_amdgcn_sched_barrier(0);
    asm volatile("s_waitcnt vmcnt(8)" ::: "memory");
    __builtin_amdgcn_s_barrier();
  }
#undef STG_A
#undef STG_B
#undef RD_A4
#undef RD_B4
#undef MMQ

  if (z < 2) {  // fused RoPE on Q/K; Q additionally pre-scaled by SCALE*log2(e)
    const float qs = (z == 0) ? (0.125f * 1.44269504088896340736f) : 1.0f;
#pragma unroll
    for (int mi = 0; mi < 8; ++mi)
#pragma unroll
      for (int r = 0; r < 4; ++r) {
        int row = m0 + wy * 128 + mi * 16 + quad * 4 + r;
        int b_ = row >> 11, s_ = row & 2047;
        int pos = pos_ids[b_ * 2048 + s_];
        const float* cb = cosb + (size_t)pos * 64;
        const float* sb = sinb + (size_t)pos * 64;
#pragma unroll
        for (int ni = 0; ni < 2; ++ni) {
          int d0 = ni * 16 + n16;
          float c0 = cb[d0] * qs, s0 = sb[d0] * qs;
          float c1 = cb[d0 + 32] * qs, s1 = sb[d0 + 32] * qs;
          float x0 = acc[mi][ni][r], x1 = acc[mi][ni + 2][r];
          acc[mi][ni][r]     = x0 * c0 - x1 * s0;
          acc[mi][ni + 2][r] = x1 * c1 + x0 * s1;
        }
      }
    unsigned short* dst = (z == 0) ? outQ : outK;
#pragma unroll
    for (int mi = 0; mi < 8; ++mi)
#pragma unroll
      for (int ni = 0; ni < 4; ++ni)
#pragma unroll
        for (int r = 0; r < 4; ++r) {
          int row = m0 + wy * 128 + mi * 16 + quad * 4 + r;
          int col = n0 + wx * 64 + ni * 16 + n16;
          int b_ = row >> 11, s_ = row & 2047, h_ = col >> 6, d_ = col & 63;
          dst[(((size_t)b_ * 16 + h_) * 2048 + s_) * 64 + d_] = f2bf(acc[mi][ni][r]);
        }
    return;
  }

  // z == 2: V^T fused write: VT[((b*16+h)*64+d)*2048 + s]; 4 consecutive s per lane
#pragma unroll
  for (int mi = 0; mi < 8; ++mi)
#pragma unroll
    for (int ni = 0; ni < 4; ++ni) {
      int row = m0 + wy * 128 + mi * 16 + quad * 4;  // +r stays within one b
      int b_ = row >> 11, s_ = row & 2047;
      int col = n0 + wx * 64 + ni * 16 + n16;
      int h_ = col >> 6, d_ = col & 63;
      ushortx4 u;
#pragma unroll
      for (int r = 0; r < 4; ++r) u[r] = f2bf(acc[mi][ni][r]);
      *(ushortx4*)(&outVT[(((size_t)b_ * 16 + h_) * 64 + d_) * 2048 + s_]) = u;
    }
}

// ---------------- Wo GEMM: 128x128 tile (R1-proven structure, ~505 TF), BK=32 dbuf ----
// M=4096, N=1024 -> 256 blocks (1/CU). id = bx + 8*by, m fastest => xcd = id%8 = m%8:
// each A-panel's 8 n-blocks land on ONE XCD (A L2-pinned); B (2MB) replicated per XCD.
__global__ __launch_bounds__(256) void wo128_kernel(const unsigned short* __restrict__ A,
                                                    const unsigned short* __restrict__ BT,
                                                    float* __restrict__ outF) {
  const int K = 1024, N = 1024;
  int id = blockIdx.x + 8 * blockIdx.y;
  int m_idx = id & 31, n_idx = id >> 5;
  int m0 = m_idx * 128, n0 = n_idx * 128;
  int t = threadIdx.x, lane = t & 63, w = t >> 6;
  int wy = w >> 1, wx = w & 1;
  int n16 = lane & 15, quad = lane >> 4;
  __shared__ __align__(16) unsigned short sA0[128 * 32];
  __shared__ __align__(16) unsigned short sA1[128 * 32];
  __shared__ __align__(16) unsigned short sB0[128 * 32];
  __shared__ __align__(16) unsigned short sB1[128 * 32];

  int r4 = lane >> 2, c4 = lane & 3;
  const char* gA = (const char*)(A + (size_t)(m0 + w * 32 + r4) * K) + ((c4 ^ (r4 & 3)) * 16);
  const char* gB = (const char*)(BT + (size_t)(n0 + w * 32 + r4) * K) + ((c4 ^ (r4 & 3)) * 16);
  const size_t row16 = (size_t)16 * K * 2;

  f32x4 acc[4][4];
#pragma unroll
  for (int i = 0; i < 4; ++i)
#pragma unroll
    for (int j = 0; j < 4; ++j) acc[i][j] = f32x4{0.f, 0.f, 0.f, 0.f};

#define WSTAGE(kk_, SA, SB)                                                     \
  do {                                                                          \
    GLL16(gA + (size_t)(kk_) * 2, SA + (w * 32) * 32);                          \
    GLL16(gA + (size_t)(kk_) * 2 + row16, SA + (w * 32 + 16) * 32);             \
    GLL16(gB + (size_t)(kk_) * 2, SB + (w * 32) * 32);                          \
    GLL16(gB + (size_t)(kk_) * 2 + row16, SB + (w * 32 + 16) * 32);             \
  } while (0)

#define WCOMPUTE(SA, SB)                                                        \
  do {                                                                          \
    bf16x8 a[4], b[4];                                                          \
    int cs = (quad ^ (n16 & 3)) * 8;                                            \
    _Pragma("unroll") for (int i = 0; i < 4; ++i) {                             \
      a[i] = *(const bf16x8*)(&SA[(wy * 64 + i * 16 + n16) * 32 + cs]);         \
      b[i] = *(const bf16x8*)(&SB[(wx * 64 + i * 16 + n16) * 32 + cs]);         \
    }                                                                           \
    _Pragma("unroll") for (int mt = 0; mt < 4; ++mt)                            \
      _Pragma("unroll") for (int nt = 0; nt < 4; ++nt)                          \
        acc[mt][nt] = __builtin_amdgcn_mfma_f32_16x16x32_bf16(                  \
            a[mt], b[nt], acc[mt][nt], 0, 0, 0);                                \
  } while (0)

  WSTAGE(0, sA0, sB0);
  for (int kk = 0; kk < K;) {
    __syncthreads();
    if (kk + 32 < K) WSTAGE(kk + 32, sA1, sB1);
    WCOMPUTE(sA0, sB0);
    kk += 32;
    if (kk >= K) break;
    __syncthreads();
    if (kk + 32 < K) WSTAGE(kk + 32, sA0, sB0);
    WCOMPUTE(sA1, sB1);
    kk += 32;
  }
#undef WSTAGE
#undef WCOMPUTE

#pragma unroll
  for (int mt = 0; mt < 4; ++mt)
#pragma unroll
    for (int nt = 0; nt < 4; ++nt)
#pragma unroll
      for (int r = 0; r < 4; ++r) {
        int row = m0 + wy * 64 + mt * 16 + quad * 4 + r;
        int col = n0 + wx * 64 + nt * 16 + n16;
        outF[(size_t)row * N + col] = acc[mt][nt][r];
      }
}

// ---------------- Flash attention: in-block split-k (8 waves), S^T orientation ----
// Q pre-scaled by SCALE*log2e in the QKV epilogue -> scores are already exp2-domain.
// K AND V staged via GLL into LDS (prefetch distance = 1 tile, V read once per
// split-group). T13 defer-max (skip o-rescale unless __all(rm <= mst+8) fails).
__global__ __launch_bounds__(512) void attn_kernel(const unsigned short* __restrict__ Q,
                                                   const unsigned short* __restrict__ Kk,
                                                   const unsigned short* __restrict__ VT,
                                                   unsigned short* __restrict__ O) {
  int bh = blockIdx.x;
  int qt = (int)(gridDim.y - 1 - blockIdx.y);  // LPT
  int t = threadIdx.x;
  int lane = t & 63;
  int w = t >> 6;          // 0..7
  int g = w >> 2;          // split group
  int w4 = w & 3;          // wave within group
  int n16 = lane & 15, quad = lane >> 4;
  int r8 = lane >> 3, c8 = lane & 7;
  const unsigned short* Qb = Q + (size_t)bh * 2048 * 64;
  const unsigned short* Kb = Kk + (size_t)bh * 2048 * 64;
  const unsigned short* Vb = VT + (size_t)bh * 64 * 2048;

  __shared__ __align__(16) unsigned short sKV[2 * 2 * 2 * 4096];
  __shared__ __align__(16) unsigned short sP[8][16 * 64];
  unsigned short* spW = sP[w];
  unsigned short* gBase = sKV + g * 16384;

  int b_ = bh >> 4, h_ = bh & 15;
  int nk = qt + 1;
  int u = (nk + 1) >> 1;
  int beg = g ? u : 0;
  int end = g ? nk : u;
  int qg = qt * 64 + w4 * 16 + n16;  // this lane's q-row

  bf16x8 aQ[2];
#pragma unroll
  for (int kb = 0; kb < 2; ++kb)
    aQ[kb] = *(const bf16x8*)(Qb + (size_t)qg * 64 + kb * 32 + quad * 8);

  f32x4 o[4];
  float mst = -3e38f, lst = 0.f;
#pragma unroll
  for (int ct = 0; ct < 4; ++ct) o[ct] = f32x4{0.f, 0.f, 0.f, 0.f};

#define ASTAGE(kt_, BUF)                                                                  \
  do {                                                                                    \
    const unsigned short* kg_ = Kb + (size_t)((kt_) * 64 + w4 * 16) * 64;                 \
    const unsigned short* vg_ = Vb + (size_t)(w4 * 16) * 2048 + (kt_) * 64;               \
    unsigned short* dK = gBase + (BUF) * 8192 + (w4 * 16) * 64;                           \
    unsigned short* dV = dK + 4096;                                                       \
    GLL16(kg_ + (size_t)r8 * 64 + (c8 ^ r8) * 8, dK);                                     \
    GLL16(kg_ + (size_t)(8 + r8) * 64 + (c8 ^ r8) * 8, dK + 8 * 64);                      \
    GLL16(vg_ + (size_t)r8 * 2048 + (c8 ^ r8) * 8, dV);                                   \
    GLL16(vg_ + (size_t)(8 + r8) * 2048 + (c8 ^ r8) * 8, dV + 8 * 64);                    \
  } while (0)

#define ACOMPUTE(kt_, BUF)                                                                \
  do {                                                                                    \
    const unsigned short* kT_ = gBase + (BUF) * 8192;                                     \
    const unsigned short* vT_ = kT_ + 4096;                                               \
    f32x4 sc[4]; /* S^T: D[m=k][n=q], A=K-frag, B=Q-frag */                               \
    _Pragma("unroll") for (int mt = 0; mt < 4; ++mt) {                                    \
      const unsigned short* kr = &kT_[(mt * 16 + n16) * 64];                              \
      bf16x8 ka0 = *(const bf16x8*)(kr + ((quad ^ (n16 & 7)) * 8));                       \
      bf16x8 ka1 = *(const bf16x8*)(kr + (((4 + quad) ^ (n16 & 7)) * 8));                 \
      f32x4 zv = f32x4{0.f, 0.f, 0.f, 0.f};                                               \
      zv = __builtin_amdgcn_mfma_f32_16x16x32_bf16(ka0, aQ[0], zv, 0, 0, 0);              \
      sc[mt] = __builtin_amdgcn_mfma_f32_16x16x32_bf16(ka1, aQ[1], zv, 0, 0, 0);          \
    }                                                                                     \
    float p[4][4];                                                                        \
    _Pragma("unroll") for (int mt = 0; mt < 4; ++mt)                                      \
      _Pragma("unroll") for (int r = 0; r < 4; ++r) p[mt][r] = sc[mt][r];                 \
    if ((kt_) == nk - 1) { /* diagonal tile: mask k > q */                                \
      int kb0 = (kt_) * 64 + quad * 4;                                                    \
      _Pragma("unroll") for (int mt = 0; mt < 4; ++mt)                                    \
        _Pragma("unroll") for (int r = 0; r < 4; ++r)                                     \
          if (kb0 + mt * 16 + r > qg) p[mt][r] = -3e38f;                                  \
    }                                                                                     \
    float rm = p[0][0];                                                                   \
    _Pragma("unroll") for (int mt = 0; mt < 4; ++mt)                                      \
      _Pragma("unroll") for (int r = 0; r < 4; ++r) rm = fmaxf(rm, p[mt][r]);             \
    rm = fmaxf(rm, __shfl_xor(rm, 16));                                                   \
    rm = fmaxf(rm, __shfl_xor(rm, 32));                                                   \
    if (!__all(rm <= mst + 8.f)) { /* T13 defer-max: rescale only on real growth */       \
      float mn = fmaxf(mst, rm);                                                          \
      float al = exp2f(mst - mn);                                                         \
      mst = mn;                                                                           \
      lst *= al;                                                                          \
      _Pragma("unroll") for (int ct = 0; ct < 4; ++ct)                                    \
        _Pragma("unroll") for (int r = 0; r < 4; ++r) o[ct][r] *= al;                     \
    }                                                                                     \
    float rs = 0.f;                                                                       \
    _Pragma("unroll") for (int mt = 0; mt < 4; ++mt)                                      \
      _Pragma("unroll") for (int r = 0; r < 4; ++r) {                                     \
        p[mt][r] = exp2f(p[mt][r] - mst);                                                 \
        rs += p[mt][r];                                                                   \
      }                                                                                   \
    lst += rs;                                                                            \
    _Pragma("unroll") for (int mt = 0; mt < 4; ++mt) {                                    \
      ushortx4 uu;                                                                        \
      _Pragma("unroll") for (int r = 0; r < 4; ++r) uu[r] = f2bf_fast(p[mt][r]);          \
      int ch = (mt * 2 + (quad >> 1)) ^ (n16 & 7);                                        \
      *(ushortx4*)(&spW[n16 * 64 + ch * 8 + (quad & 1) * 4]) = uu;                        \
    }                                                                                     \
    __builtin_amdgcn_s_waitcnt(0xC07F); /* lgkmcnt(0); GLL prefetch stays in flight */    \
    bf16x8 aP0 = *(const bf16x8*)(&spW[n16 * 64 + ((quad ^ (n16 & 7)) * 8)]);             \
    bf16x8 aP1 = *(const bf16x8*)(&spW[n16 * 64 + (((4 + quad) ^ (n16 & 7)) * 8)]);       \
    _Pragma("unroll") for (int ct = 0; ct < 4; ++ct) {                                    \
      const unsigned short* vr = &vT_[(ct * 16 + n16) * 64];                              \
      bf16x8 va0 = *(const bf16x8*)(vr + ((quad ^ (n16 & 7)) * 8));                       \
      bf16x8 va1 = *(const bf16x8*)(vr + (((4 + quad) ^ (n16 & 7)) * 8));                 \
      o[ct] = __builtin_amdgcn_mfma_f32_16x16x32_bf16(va0, aP0, o[ct], 0, 0, 0);          \
      o[ct] = __builtin_amdgcn_mfma_f32_16x16x32_bf16(va1, aP1, o[ct], 0, 0, 0);          \
    }                                                                                     \
  } while (0)

  if (beg < end) ASTAGE(beg, 0);
  int it = 0;
  while (it < u) {
    __syncthreads();  // drains loads into buf0 (u is block-uniform)
    {
      int kt = beg + it;
      if (kt + 1 < end) ASTAGE(kt + 1, 1);
      if (kt < end) ACOMPUTE(kt, 0);
    }
    if (++it >= u) break;
    __syncthreads();  // drains loads into buf1
    {
      int kt = beg + it;
      if (kt + 1 < end) ASTAGE(kt + 1, 0);
      if (kt < end) ACOMPUTE(kt, 1);
    }
    ++it;
  }
#undef ASTAGE
#undef ACOMPUTE

  // finish lane-partial l (cross-quad k-partials)
  lst += __shfl_xor(lst, 16);
  lst += __shfl_xor(lst, 32);

  // merge the two split-k partials via LDS
  __syncthreads();
  float* scratch = (float*)sKV;  // 18 floats per (w4,lane); stride 18 -> 2-way banks (free)
  int sidx = (w4 * 64 + lane) * 18;
  if (g == 1) {
#pragma unroll
    for (int ct = 0; ct < 4; ++ct)
#pragma unroll
      for (int r = 0; r < 4; ++r) scratch[sidx + ct * 4 + r] = o[ct][r];
    scratch[sidx + 16] = mst;
    scratch[sidx + 17] = lst;
  }
  __syncthreads();
  if (g == 0) {
    float m1 = scratch[sidx + 16], l1 = scratch[sidx + 17];
    float m = fmaxf(mst, m1);
    float a0 = exp2f(mst - m), a1 = exp2f(m1 - m);
    float inv = 1.0f / (lst * a0 + l1 * a1);
#pragma unroll
    for (int ct = 0; ct < 4; ++ct) {
      ushortx4 uo;
#pragma unroll
      for (int r = 0; r < 4; ++r) {
        float v = (o[ct][r] * a0 + scratch[sidx + ct * 4 + r] * a1) * inv;
        uo[r] = f2bf(v);
      }
      size_t addr = ((size_t)b_ * 2048 + qg) * 1024 + h_ * 64 + ct * 16 + quad * 4;
      *(ushortx4*)(&O[addr]) = uo;
    }
  }
}

// ---------------- launch ----------------
extern "C" void kernel_launch(void* const* d_in, const int* in_sizes, int n_in,
                              void* d_out, int out_size, void* d_ws, size_t ws_size,
                              hipStream_t stream) {
  const float* X    = (const float*)d_in[0];
  const int*   pos  = (const int*)d_in[2];
  const float* cosb = (const float*)d_in[3];
  const float* sinb = (const float*)d_in[4];
  const float* Wq   = (const float*)d_in[5];
  const float* Wk   = (const float*)d_in[6];
  const float* Wv   = (const float*)d_in[7];
  const float* Wo   = (const float*)d_in[8];
  float* out = (float*)d_out;

  char* ws = (char*)d_ws;
  const size_t SZ_X = 4096UL * 1024 * 2;
  const size_t SZ_W = 1024UL * 1024 * 2;
  unsigned short* Xbf = (unsigned short*)(ws);
  unsigned short* WTq = (unsigned short*)(ws + SZ_X);
  unsigned short* WTk = (unsigned short*)(ws + SZ_X + SZ_W);
  unsigned short* WTv = (unsigned short*)(ws + SZ_X + 2 * SZ_W);
  unsigned short* WTo = (unsigned short*)(ws + SZ_X + 3 * SZ_W);
  unsigned short* Qbf = (unsigned short*)(ws + SZ_X + 4 * SZ_W);
  unsigned short* Kbf = (unsigned short*)(ws + 2 * SZ_X + 4 * SZ_W);
  unsigned short* VTr = (unsigned short*)(ws + 3 * SZ_X + 4 * SZ_W);
  unsigned short* Obf = (unsigned short*)(ws + 4 * SZ_X + 4 * SZ_W);

  prep_kernel<<<dim3(32, 32, 6), dim3(32, 8), 0, stream>>>(
      X, Wq, Wk, Wv, Wo, Xbf, WTq, WTk, WTv, WTo);

  // QKV projections + fused RoPE (Q pre-scaled) + fused V-transpose, 256^2 counted-vmcnt
  gemm256_kernel<<<dim3(8, 24), 512, 0, stream>>>(Xbf, WTq, WTk, WTv,
                                                  Qbf, Kbf, VTr,
                                                  pos, cosb, sinb);

  attn_kernel<<<dim3(32, 32), 512, 0, stream>>>(Qbf, Kbf, VTr, Obf);

  // Wo GEMM: 128x128-tile proven structure (replaces 64x64)
  wo128_kernel<<<dim3(8, 32), 256, 0, stream>>>(Obf, WTo, out);
}

// Round 7
// 201.740 us; speedup vs baseline: 1.0221x; 1.0221x over previous
//
#include <hip/hip_runtime.h>

typedef __bf16 bf16x8 __attribute__((ext_vector_type(8)));
typedef float  f32x4  __attribute__((ext_vector_type(4)));
typedef unsigned short ushortx8 __attribute__((ext_vector_type(8)));
typedef unsigned short ushortx4 __attribute__((ext_vector_type(4)));

static __device__ __forceinline__ unsigned short f2bf(float f) {
  unsigned int u = __builtin_bit_cast(unsigned int, f);
  u += 0x7FFFu + ((u >> 16) & 1u);
  return (unsigned short)(u >> 16);
}
static __device__ __forceinline__ unsigned short f2bf_fast(float f) {  // round-half-up
  unsigned int u = __builtin_bit_cast(unsigned int, f);
  return (unsigned short)((u + 0x8000u) >> 16);
}

#define GLL16(gp, lp) __builtin_amdgcn_global_load_lds(                       \
    (const __attribute__((address_space(1))) void*)(gp),                      \
    (__attribute__((address_space(3))) void*)(lp), 16, 0, 0)

// ---------------- prep: z<4 -> transpose+cast W; z>=4 -> cast X fp32->bf16 ----------------
__global__ __launch_bounds__(256) void prep_kernel(const float* __restrict__ X,
                                                   const float* __restrict__ W0,
                                                   const float* __restrict__ W1,
                                                   const float* __restrict__ W2,
                                                   const float* __restrict__ W3,
                                                   unsigned short* __restrict__ Xbf,
                                                   unsigned short* __restrict__ D0,
                                                   unsigned short* __restrict__ D1,
                                                   unsigned short* __restrict__ D2,
                                                   unsigned short* __restrict__ D3) {
  int z = blockIdx.z;
  if (z >= 4) {  // cast 4096x1024 fp32 -> bf16; z in {4,5}
    long bid = (long)(z - 4) * 1024 + blockIdx.y * 32 + blockIdx.x;
    int tl = threadIdx.y * 32 + threadIdx.x;
    long i = bid * 2048 + (long)tl * 8;
    float4 f0 = *(const float4*)(X + i);
    float4 f1 = *(const float4*)(X + i + 4);
    ushortx8 u;
    u[0] = f2bf(f0.x); u[1] = f2bf(f0.y); u[2] = f2bf(f0.z); u[3] = f2bf(f0.w);
    u[4] = f2bf(f1.x); u[5] = f2bf(f1.y); u[6] = f2bf(f1.z); u[7] = f2bf(f1.w);
    *(ushortx8*)(Xbf + i) = u;
    return;
  }
  const float* src = (z == 0) ? W0 : (z == 1) ? W1 : (z == 2) ? W2 : W3;
  unsigned short* dst = (z == 0) ? D0 : (z == 1) ? D1 : (z == 2) ? D2 : D3;
  const int R = 1024, C = 1024;
  __shared__ unsigned short t[32][33];
  int c = blockIdx.x * 32 + threadIdx.x;
#pragma unroll
  for (int i = 0; i < 4; ++i) {
    int r = blockIdx.y * 32 + threadIdx.y + i * 8;
    t[threadIdx.y + i * 8][threadIdx.x] = f2bf(src[(size_t)r * C + c]);
  }
  __syncthreads();
  int rr = blockIdx.y * 32 + threadIdx.x;
#pragma unroll
  for (int i = 0; i < 4; ++i) {
    int cc = blockIdx.x * 32 + threadIdx.y + i * 8;
    dst[(size_t)cc * R + rr] = t[threadIdx.x][threadIdx.y + i * 8];
  }
}

// ---------------- QKV GEMM: 128x128 tile, BK=32, 3-deep LDS ring, counted vmcnt ----
// R1-proven fragment/address patterns + R3-proven ring arithmetic, 48KB LDS ->
// 3 blocks/CU residency (TLP hides the counted wait). 4 loads/thread/tile, prefetch
// distance 2: during tile kt stage kt+2 into buf[(kt+2)%3] (dead since kt-1's trailing
// barrier). Trailing vmcnt(4): leaves kt+2's 4 loads in flight, secures kt+1.
// z: 0=Q (RoPE, pre-scaled by SCALE*log2e), 1=K (RoPE), 2=V^T (fused transpose).
__global__ __launch_bounds__(256, 3) void qkvr_kernel(
    const unsigned short* __restrict__ A,
    const unsigned short* __restrict__ BT0,
    const unsigned short* __restrict__ BT1,
    const unsigned short* __restrict__ BT2,
    unsigned short* __restrict__ outQ,
    unsigned short* __restrict__ outK,
    unsigned short* __restrict__ outVT,
    const int* __restrict__ pos_ids,
    const float* __restrict__ cosb,
    const float* __restrict__ sinb) {
  const int K = 1024;
  int id = blockIdx.x + 8 * (blockIdx.y + 32 * blockIdx.z);
  int m_idx = id & 31;         // m fastest => xcd = id%8 = m_idx%8
  int nzi = id >> 5;
  int n_idx = nzi & 7;
  int z = nzi >> 3;
  const unsigned short* BT = (z == 0) ? BT0 : (z == 1 ? BT1 : BT2);
  int n0 = n_idx * 128, m0 = m_idx * 128;
  int t = threadIdx.x, lane = t & 63, w = t >> 6;
  int wy = w >> 1, wx = w & 1;
  int n16 = lane & 15, quad = lane >> 4;

  __shared__ __align__(16) unsigned short sA[3][128][32];
  __shared__ __align__(16) unsigned short sB[3][128][32];
  __shared__ __align__(16) unsigned short sDummy[512];  // tail sink (never read)
  const int BUFE = 128 * 32;

  int r4 = lane >> 2, c4 = lane & 3;
  const char* gA = (const char*)(A + (size_t)(m0 + w * 32 + r4) * K) + ((c4 ^ (r4 & 3)) * 16);
  const char* gB = (const char*)(BT + (size_t)(n0 + w * 32 + r4) * K) + ((c4 ^ (r4 & 3)) * 16);
  const size_t row16 = (size_t)16 * K * 2;
  unsigned short* stA = &sA[0][w * 32][0];
  unsigned short* stB = &sB[0][w * 32][0];

  int cs = (quad ^ (n16 & 3)) * 8;
  const unsigned short* rdA = &sA[0][wy * 64 + n16][0] + cs;
  const unsigned short* rdB = &sB[0][wx * 64 + n16][0] + cs;

  f32x4 acc[4][4];
#pragma unroll
  for (int i = 0; i < 4; ++i)
#pragma unroll
    for (int j = 0; j < 4; ++j) acc[i][j] = f32x4{0.f, 0.f, 0.f, 0.f};

  bf16x8 a[4], b[4];

#define QSTG(tt, dA, dB)                                                        \
  do {                                                                          \
    GLL16(gA + (size_t)(tt) * 64, (dA));                                        \
    GLL16(gA + (size_t)(tt) * 64 + row16, (dA) + 16 * 32);                      \
    GLL16(gB + (size_t)(tt) * 64, (dB));                                        \
    GLL16(gB + (size_t)(tt) * 64 + row16, (dB) + 16 * 32);                      \
  } while (0)

#define QRD(bufi)                                                               \
  do {                                                                          \
    _Pragma("unroll") for (int i = 0; i < 4; ++i) {                             \
      a[i] = *(const bf16x8*)(rdA + (bufi) * BUFE + (i * 16) * 32);             \
      b[i] = *(const bf16x8*)(rdB + (bufi) * BUFE + (i * 16) * 32);             \
    }                                                                           \
  } while (0)

#define QMM                                                                     \
  do {                                                                          \
    _Pragma("unroll") for (int mt = 0; mt < 4; ++mt)                            \
      _Pragma("unroll") for (int nt = 0; nt < 4; ++nt)                          \
        acc[mt][nt] = __builtin_amdgcn_mfma_f32_16x16x32_bf16(                  \
            a[mt], b[nt], acc[mt][nt], 0, 0, 0);                                \
  } while (0)

  // prologue: stage tiles 0,1 (8 loads); vmcnt(4) -> tile0 landed, tile1 in flight
  QSTG(0, stA, stB);
  QSTG(1, stA + BUFE, stB + BUFE);
  asm volatile("s_waitcnt vmcnt(4)" ::: "memory");
  __builtin_amdgcn_s_barrier();

#pragma unroll 3
  for (int kt = 0; kt < 30; ++kt) {
    int buf = kt % 3;
    int pfb = (kt + 2) % 3;
    QRD(buf);
    QSTG(kt + 2, stA + pfb * BUFE, stB + pfb * BUFE);
    QMM;
    asm volatile("s_waitcnt vmcnt(4)" ::: "memory");
    __builtin_amdgcn_s_barrier();
  }
  // tail: tiles 30 (buf 0) and 31 (buf 1); dummy staging keeps vmcnt uniform
  {
    QRD(0);
    QSTG(31, sDummy, sDummy);  // addresses valid (tile31 global), dest is sink
    QMM;
    asm volatile("s_waitcnt vmcnt(4)" ::: "memory");
    __builtin_amdgcn_s_barrier();
  }
  {
    QRD(1);
    QSTG(31, sDummy, sDummy);
    QMM;
    asm volatile("s_waitcnt vmcnt(0)" ::: "memory");  // drain sinks before epilogue
  }
#undef QSTG
#undef QRD
#undef QMM

  if (z < 2) {  // fused RoPE on Q/K; Q additionally pre-scaled by SCALE*log2(e)
    const float qs = (z == 0) ? (0.125f * 1.44269504088896340736f) : 1.0f;
#pragma unroll
    for (int mt = 0; mt < 4; ++mt)
#pragma unroll
      for (int r = 0; r < 4; ++r) {
        int row = m0 + wy * 64 + mt * 16 + quad * 4 + r;
        int b_ = row >> 11, s_ = row & 2047;
        int pos = pos_ids[b_ * 2048 + s_];
        const float* cb = cosb + (size_t)pos * 64;
        const float* sb = sinb + (size_t)pos * 64;
#pragma unroll
        for (int nt = 0; nt < 2; ++nt) {
          int d0 = nt * 16 + n16;
          float c0 = cb[d0] * qs, s0 = sb[d0] * qs;
          float c1 = cb[d0 + 32] * qs, s1 = sb[d0 + 32] * qs;
          float x0 = acc[mt][nt][r], x1 = acc[mt][nt + 2][r];
          acc[mt][nt][r]     = x0 * c0 - x1 * s0;
          acc[mt][nt + 2][r] = x1 * c1 + x0 * s1;
        }
      }
    unsigned short* dst = (z == 0) ? outQ : outK;
#pragma unroll
    for (int mt = 0; mt < 4; ++mt)
#pragma unroll
      for (int nt = 0; nt < 4; ++nt)
#pragma unroll
        for (int r = 0; r < 4; ++r) {
          int row = m0 + wy * 64 + mt * 16 + quad * 4 + r;
          int col = n0 + wx * 64 + nt * 16 + n16;
          int b_ = row >> 11, s_ = row & 2047, h_ = col >> 6, d_ = col & 63;
          dst[(((size_t)b_ * 16 + h_) * 2048 + s_) * 64 + d_] = f2bf(acc[mt][nt][r]);
        }
    return;
  }

  // z == 2: V^T fused write: VT[((b*16+h)*64+d)*2048 + s]; 4 consecutive s per lane
#pragma unroll
  for (int mt = 0; mt < 4; ++mt)
#pragma unroll
    for (int nt = 0; nt < 4; ++nt) {
      int row = m0 + wy * 64 + mt * 16 + quad * 4;  // +r stays within one b
      int b_ = row >> 11, s_ = row & 2047;
      int col = n0 + wx * 64 + nt * 16 + n16;
      int h_ = col >> 6, d_ = col & 63;
      ushortx4 u;
#pragma unroll
      for (int r = 0; r < 4; ++r) u[r] = f2bf(acc[mt][nt][r]);
      *(ushortx4*)(&outVT[(((size_t)b_ * 16 + h_) * 64 + d_) * 2048 + s_]) = u;
    }
}

// ---------------- Wo GEMM: 128x64 tile, BK=32, 3-deep ring, counted vmcnt ----
// M=4096 x N=1024 -> 512 blocks (2/CU). id = bx + 8*by, m fastest -> xcd = m%8
// (A-panels L2-pinned per XCD). 3 loads/thread/tile (2A+1B) -> trailing vmcnt(3).
__global__ __launch_bounds__(256) void wor_kernel(const unsigned short* __restrict__ A,
                                                  const unsigned short* __restrict__ BT,
                                                  float* __restrict__ outF) {
  const int K = 1024, N = 1024;
  int id = blockIdx.x + 8 * blockIdx.y;  // grid (8,64)
  int m_idx = id & 31, n_idx = id >> 5;
  int m0 = m_idx * 128, n0 = n_idx * 64;
  int t = threadIdx.x, lane = t & 63, w = t >> 6;
  int wy = w >> 1, wx = w & 1;
  int n16 = lane & 15, quad = lane >> 4;

  __shared__ __align__(16) unsigned short sA[3][128][32];
  __shared__ __align__(16) unsigned short sB[3][64][32];
  __shared__ __align__(16) unsigned short sDummy[512];
  const int BUFA = 128 * 32, BUFB = 64 * 32;

  int r4 = lane >> 2, c4 = lane & 3;
  const char* gA = (const char*)(A + (size_t)(m0 + w * 32 + r4) * K) + ((c4 ^ (r4 & 3)) * 16);
  const char* gB = (const char*)(BT + (size_t)(n0 + w * 16 + r4) * K) + ((c4 ^ (r4 & 3)) * 16);
  const size_t row16 = (size_t)16 * K * 2;
  unsigned short* stA = &sA[0][w * 32][0];
  unsigned short* stB = &sB[0][w * 16][0];

  int cs = (quad ^ (n16 & 3)) * 8;
  const unsigned short* rdA = &sA[0][wy * 64 + n16][0] + cs;
  const unsigned short* rdB = &sB[0][wx * 32 + n16][0] + cs;

  f32x4 acc[4][2];
#pragma unroll
  for (int i = 0; i < 4; ++i)
#pragma unroll
    for (int j = 0; j < 2; ++j) acc[i][j] = f32x4{0.f, 0.f, 0.f, 0.f};

  bf16x8 a[4], b[2];

#define WSTG(tt, dA, dB)                                                        \
  do {                                                                          \
    GLL16(gA + (size_t)(tt) * 64, (dA));                                        \
    GLL16(gA + (size_t)(tt) * 64 + row16, (dA) + 16 * 32);                      \
    GLL16(gB + (size_t)(tt) * 64, (dB));                                        \
  } while (0)

#define WRD(bufi)                                                               \
  do {                                                                          \
    _Pragma("unroll") for (int i = 0; i < 4; ++i)                               \
      a[i] = *(const bf16x8*)(rdA + (bufi) * BUFA + (i * 16) * 32);             \
    _Pragma("unroll") for (int j = 0; j < 2; ++j)                               \
      b[j] = *(const bf16x8*)(rdB + (bufi) * BUFB + (j * 16) * 32);             \
  } while (0)

#define WMM                                                                     \
  do {                                                                          \
    _Pragma("unroll") for (int mt = 0; mt < 4; ++mt)                            \
      _Pragma("unroll") for (int nt = 0; nt < 2; ++nt)                          \
        acc[mt][nt] = __builtin_amdgcn_mfma_f32_16x16x32_bf16(                  \
            a[mt], b[nt], acc[mt][nt], 0, 0, 0);                                \
  } while (0)

  WSTG(0, stA, stB);
  WSTG(1, stA + BUFA, stB + BUFB);
  asm volatile("s_waitcnt vmcnt(3)" ::: "memory");
  __builtin_amdgcn_s_barrier();

#pragma unroll 3
  for (int kt = 0; kt < 30; ++kt) {
    int buf = kt % 3;
    int pfb = (kt + 2) % 3;
    WRD(buf);
    WSTG(kt + 2, stA + pfb * BUFA, stB + pfb * BUFB);
    WMM;
    asm volatile("s_waitcnt vmcnt(3)" ::: "memory");
    __builtin_amdgcn_s_barrier();
  }
  {
    WRD(0);
    WSTG(31, sDummy, sDummy);
    WMM;
    asm volatile("s_waitcnt vmcnt(3)" ::: "memory");
    __builtin_amdgcn_s_barrier();
  }
  {
    WRD(1);
    WSTG(31, sDummy, sDummy);
    WMM;
    asm volatile("s_waitcnt vmcnt(0)" ::: "memory");
  }
#undef WSTG
#undef WRD
#undef WMM

#pragma unroll
  for (int mt = 0; mt < 4; ++mt)
#pragma unroll
    for (int nt = 0; nt < 2; ++nt)
#pragma unroll
      for (int r = 0; r < 4; ++r) {
        int row = m0 + wy * 64 + mt * 16 + quad * 4 + r;
        int col = n0 + wx * 32 + nt * 16 + n16;
        outF[(size_t)row * N + col] = acc[mt][nt][r];
      }
}

// ---------------- Flash attention: in-block split-k (8 waves), S^T orientation ----
// Q pre-scaled by SCALE*log2e in the QKV epilogue -> scores are already exp2-domain.
// K AND V staged via GLL into LDS (prefetch distance = 1 tile, V read once per
// split-group). T13 defer-max (skip o-rescale unless __all(rm <= mst+8) fails).
__global__ __launch_bounds__(512) void attn_kernel(const unsigned short* __restrict__ Q,
                                                   const unsigned short* __restrict__ Kk,
                                                   const unsigned short* __restrict__ VT,
                                                   unsigned short* __restrict__ O) {
  int bh = blockIdx.x;
  int qt = (int)(gridDim.y - 1 - blockIdx.y);  // LPT
  int t = threadIdx.x;
  int lane = t & 63;
  int w = t >> 6;          // 0..7
  int g = w >> 2;          // split group
  int w4 = w & 3;          // wave within group
  int n16 = lane & 15, quad = lane >> 4;
  int r8 = lane >> 3, c8 = lane & 7;
  const unsigned short* Qb = Q + (size_t)bh * 2048 * 64;
  const unsigned short* Kb = Kk + (size_t)bh * 2048 * 64;
  const unsigned short* Vb = VT + (size_t)bh * 64 * 2048;

  __shared__ __align__(16) unsigned short sKV[2 * 2 * 2 * 4096];
  __shared__ __align__(16) unsigned short sP[8][16 * 64];
  unsigned short* spW = sP[w];
  unsigned short* gBase = sKV + g * 16384;

  int b_ = bh >> 4, h_ = bh & 15;
  int nk = qt + 1;
  int u = (nk + 1) >> 1;
  int beg = g ? u : 0;
  int end = g ? nk : u;
  int qg = qt * 64 + w4 * 16 + n16;  // this lane's q-row

  bf16x8 aQ[2];
#pragma unroll
  for (int kb = 0; kb < 2; ++kb)
    aQ[kb] = *(const bf16x8*)(Qb + (size_t)qg * 64 + kb * 32 + quad * 8);

  f32x4 o[4];
  float mst = -3e38f, lst = 0.f;
#pragma unroll
  for (int ct = 0; ct < 4; ++ct) o[ct] = f32x4{0.f, 0.f, 0.f, 0.f};

#define ASTAGE(kt_, BUF)                                                                  \
  do {                                                                                    \
    const unsigned short* kg_ = Kb + (size_t)((kt_) * 64 + w4 * 16) * 64;                 \
    const unsigned short* vg_ = Vb + (size_t)(w4 * 16) * 2048 + (kt_) * 64;               \
    unsigned short* dK = gBase + (BUF) * 8192 + (w4 * 16) * 64;                           \
    unsigned short* dV = dK + 4096;                                                       \
    GLL16(kg_ + (size_t)r8 * 64 + (c8 ^ r8) * 8, dK);                                     \
    GLL16(kg_ + (size_t)(8 + r8) * 64 + (c8 ^ r8) * 8, dK + 8 * 64);                      \
    GLL16(vg_ + (size_t)r8 * 2048 + (c8 ^ r8) * 8, dV);                                   \
    GLL16(vg_ + (size_t)(8 + r8) * 2048 + (c8 ^ r8) * 8, dV + 8 * 64);                    \
  } while (0)

#define ACOMPUTE(kt_, BUF)                                                                \
  do {                                                                                    \
    const unsigned short* kT_ = gBase + (BUF) * 8192;                                     \
    const unsigned short* vT_ = kT_ + 4096;                                               \
    f32x4 sc[4]; /* S^T: D[m=k][n=q], A=K-frag, B=Q-frag */                               \
    _Pragma("unroll") for (int mt = 0; mt < 4; ++mt) {                                    \
      const unsigned short* kr = &kT_[(mt * 16 + n16) * 64];                              \
      bf16x8 ka0 = *(const bf16x8*)(kr + ((quad ^ (n16 & 7)) * 8));                       \
      bf16x8 ka1 = *(const bf16x8*)(kr + (((4 + quad) ^ (n16 & 7)) * 8));                 \
      f32x4 zv = f32x4{0.f, 0.f, 0.f, 0.f};                                               \
      zv = __builtin_amdgcn_mfma_f32_16x16x32_bf16(ka0, aQ[0], zv, 0, 0, 0);              \
      sc[mt] = __builtin_amdgcn_mfma_f32_16x16x32_bf16(ka1, aQ[1], zv, 0, 0, 0);          \
    }                                                                                     \
    float p[4][4];                                                                        \
    _Pragma("unroll") for (int mt = 0; mt < 4; ++mt)                                      \
      _Pragma("unroll") for (int r = 0; r < 4; ++r) p[mt][r] = sc[mt][r];                 \
    if ((kt_) == nk - 1) { /* diagonal tile: mask k > q */                                \
      int kb0 = (kt_) * 64 + quad * 4;                                                    \
      _Pragma("unroll") for (int mt = 0; mt < 4; ++mt)                                    \
        _Pragma("unroll") for (int r = 0; r < 4; ++r)                                     \
          if (kb0 + mt * 16 + r > qg) p[mt][r] = -3e38f;                                  \
    }                                                                                     \
    float rm = p[0][0];                                                                   \
    _Pragma("unroll") for (int mt = 0; mt < 4; ++mt)                                      \
      _Pragma("unroll") for (int r = 0; r < 4; ++r) rm = fmaxf(rm, p[mt][r]);             \
    rm = fmaxf(rm, __shfl_xor(rm, 16));                                                   \
    rm = fmaxf(rm, __shfl_xor(rm, 32));                                                   \
    if (!__all(rm <= mst + 8.f)) { /* T13 defer-max: rescale only on real growth */       \
      float mn = fmaxf(mst, rm);                                                          \
      float al = exp2f(mst - mn);                                                         \
      mst = mn;                                                                           \
      lst *= al;                                                                          \
      _Pragma("unroll") for (int ct = 0; ct < 4; ++ct)                                    \
        _Pragma("unroll") for (int r = 0; r < 4; ++r) o[ct][r] *= al;                     \
    }                                                                                     \
    float rs = 0.f;                                                                       \
    _Pragma("unroll") for (int mt = 0; mt < 4; ++mt)                                      \
      _Pragma("unroll") for (int r = 0; r < 4; ++r) {                                     \
        p[mt][r] = exp2f(p[mt][r] - mst);                                                 \
        rs += p[mt][r];                                                                   \
      }                                                                                   \
    lst += rs;                                                                            \
    _Pragma("unroll") for (int mt = 0; mt < 4; ++mt) {                                    \
      ushortx4 uu;                                                                        \
      _Pragma("unroll") for (int r = 0; r < 4; ++r) uu[r] = f2bf_fast(p[mt][r]);          \
      int ch = (mt * 2 + (quad >> 1)) ^ (n16 & 7);                                        \
      *(ushortx4*)(&spW[n16 * 64 + ch * 8 + (quad & 1) * 4]) = uu;                        \
    }                                                                                     \
    __builtin_amdgcn_s_waitcnt(0xC07F); /* lgkmcnt(0); GLL prefetch stays in flight */    \
    bf16x8 aP0 = *(const bf16x8*)(&spW[n16 * 64 + ((quad ^ (n16 & 7)) * 8)]);             \
    bf16x8 aP1 = *(const bf16x8*)(&spW[n16 * 64 + (((4 + quad) ^ (n16 & 7)) * 8)]);       \
    _Pragma("unroll") for (int ct = 0; ct < 4; ++ct) {                                    \
      const unsigned short* vr = &vT_[(ct * 16 + n16) * 64];                              \
      bf16x8 va0 = *(const bf16x8*)(vr + ((quad ^ (n16 & 7)) * 8));                       \
      bf16x8 va1 = *(const bf16x8*)(vr + (((4 + quad) ^ (n16 & 7)) * 8));                 \
      o[ct] = __builtin_amdgcn_mfma_f32_16x16x32_bf16(va0, aP0, o[ct], 0, 0, 0);          \
      o[ct] = __builtin_amdgcn_mfma_f32_16x16x32_bf16(va1, aP1, o[ct], 0, 0, 0);          \
    }                                                                                     \
  } while (0)

  if (beg < end) ASTAGE(beg, 0);
  int it = 0;
  while (it < u) {
    __syncthreads();  // drains loads into buf0 (u is block-uniform)
    {
      int kt = beg + it;
      if (kt + 1 < end) ASTAGE(kt + 1, 1);
      if (kt < end) ACOMPUTE(kt, 0);
    }
    if (++it >= u) break;
    __syncthreads();  // drains loads into buf1
    {
      int kt = beg + it;
      if (kt + 1 < end) ASTAGE(kt + 1, 0);
      if (kt < end) ACOMPUTE(kt, 1);
    }
    ++it;
  }
#undef ASTAGE
#undef ACOMPUTE

  // finish lane-partial l (cross-quad k-partials)
  lst += __shfl_xor(lst, 16);
  lst += __shfl_xor(lst, 32);

  // merge the two split-k partials via LDS
  __syncthreads();
  float* scratch = (float*)sKV;  // 18 floats per (w4,lane); stride 18 -> 2-way banks (free)
  int sidx = (w4 * 64 + lane) * 18;
  if (g == 1) {
#pragma unroll
    for (int ct = 0; ct < 4; ++ct)
#pragma unroll
      for (int r = 0; r < 4; ++r) scratch[sidx + ct * 4 + r] = o[ct][r];
    scratch[sidx + 16] = mst;
    scratch[sidx + 17] = lst;
  }
  __syncthreads();
  if (g == 0) {
    float m1 = scratch[sidx + 16], l1 = scratch[sidx + 17];
    float m = fmaxf(mst, m1);
    float a0 = exp2f(mst - m), a1 = exp2f(m1 - m);
    float inv = 1.0f / (lst * a0 + l1 * a1);
#pragma unroll
    for (int ct = 0; ct < 4; ++ct) {
      ushortx4 uo;
#pragma unroll
      for (int r = 0; r < 4; ++r) {
        float v = (o[ct][r] * a0 + scratch[sidx + ct * 4 + r] * a1) * inv;
        uo[r] = f2bf(v);
      }
      size_t addr = ((size_t)b_ * 2048 + qg) * 1024 + h_ * 64 + ct * 16 + quad * 4;
      *(ushortx4*)(&O[addr]) = uo;
    }
  }
}

// ---------------- launch ----------------
extern "C" void kernel_launch(void* const* d_in, const int* in_sizes, int n_in,
                              void* d_out, int out_size, void* d_ws, size_t ws_size,
                              hipStream_t stream) {
  const float* X    = (const float*)d_in[0];
  const int*   pos  = (const int*)d_in[2];
  const float* cosb = (const float*)d_in[3];
  const float* sinb = (const float*)d_in[4];
  const float* Wq   = (const float*)d_in[5];
  const float* Wk   = (const float*)d_in[6];
  const float* Wv   = (const float*)d_in[7];
  const float* Wo   = (const float*)d_in[8];
  float* out = (float*)d_out;

  char* ws = (char*)d_ws;
  const size_t SZ_X = 4096UL * 1024 * 2;
  const size_t SZ_W = 1024UL * 1024 * 2;
  unsigned short* Xbf = (unsigned short*)(ws);
  unsigned short* WTq = (unsigned short*)(ws + SZ_X);
  unsigned short* WTk = (unsigned short*)(ws + SZ_X + SZ_W);
  unsigned short* WTv = (unsigned short*)(ws + SZ_X + 2 * SZ_W);
  unsigned short* WTo = (unsigned short*)(ws + SZ_X + 3 * SZ_W);
  unsigned short* Qbf = (unsigned short*)(ws + SZ_X + 4 * SZ_W);
  unsigned short* Kbf = (unsigned short*)(ws + 2 * SZ_X + 4 * SZ_W);
  unsigned short* VTr = (unsigned short*)(ws + 3 * SZ_X + 4 * SZ_W);
  unsigned short* Obf = (unsigned short*)(ws + 4 * SZ_X + 4 * SZ_W);

  prep_kernel<<<dim3(32, 32, 6), dim3(32, 8), 0, stream>>>(
      X, Wq, Wk, Wv, Wo, Xbf, WTq, WTk, WTv, WTo);

  // QKV projections + fused RoPE (Q pre-scaled) + fused V-transpose, 128^2 ring
  qkvr_kernel<<<dim3(8, 32, 3), 256, 0, stream>>>(Xbf, WTq, WTk, WTv,
                                                  Qbf, Kbf, VTr,
                                                  pos, cosb, sinb);

  attn_kernel<<<dim3(32, 32), 512, 0, stream>>>(Qbf, Kbf, VTr, Obf);

  // Wo GEMM: 128x64 ring, 512 blocks
  wor_kernel<<<dim3(8, 64), 256, 0, stream>>>(Obf, WTo, out);
}